// Round 14
// baseline (347.704 us; speedup 1.0000x reference)
//
#include <hip/hip_runtime.h>
#include <stdint.h>

#define T_SEQ   2048
#define HID     4096
#define NH      32
#define NKV     8
#define HD      128
#define QCOLS   6144
#define QK_SCALE 0.08838834764831845f  // 1/sqrt(128)

typedef _Float16 half_t;
typedef _Float16 half8 __attribute__((ext_vector_type(8)));
typedef _Float16 half4v __attribute__((ext_vector_type(4)));
typedef float    f32x4 __attribute__((ext_vector_type(4)));

typedef __attribute__((address_space(1))) const void cg_void;
typedef __attribute__((address_space(3))) void lds_void;

// ---------------- cast fp32 -> fp16 for X only (weights read fp32 by GEMM) --
__global__ __launch_bounds__(256) void cast_x_k(const float* __restrict__ X,
                                                half_t* __restrict__ Xh) {
  int i = blockIdx.x * 256 + threadIdx.x;   // float4 index, total 2097152
  f32x4 v = *(const f32x4*)(X + (size_t)i * 4);
  half4v o;
  o[0] = (half_t)v[0]; o[1] = (half_t)v[1]; o[2] = (half_t)v[2]; o[3] = (half_t)v[3];
  *(half4v*)(Xh + (size_t)i * 4) = o;
}

// ---------------- RoPE cos/sin tables ----------------
__global__ __launch_bounds__(256) void rope_tables_k(float* __restrict__ cs) {
  int idx = blockIdx.x * 256 + threadIdx.x;  // 2048*64
  int t = idx >> 6, i = idx & 63;
  float inv = expf(-(float)i * 0.14391156831212787f);
  float a = (float)t * inv;
  cs[idx] = cosf(a);
  cs[131072 + idx] = sinf(a);
}

// ---------- fused: RoPE apply (blocks < 20480) + V transpose (rest) ----------
__global__ __launch_bounds__(256) void rope_vt_k(half_t* __restrict__ QKV,
                                                 const float* __restrict__ cs,
                                                 half_t* __restrict__ Vt) {
  if (blockIdx.x < 20480) {
    int idx = blockIdx.x * 256 + threadIdx.x;  // 2048*40*64
    int i = idx & 63;
    int rem = idx >> 6;
    int head = rem % 40;
    int t = rem / 40;
    int colbase = (head < 32) ? head * HD : HID + (head - 32) * HD;
    size_t base = (size_t)t * QCOLS + colbase;
    float c = cs[t * 64 + i], s = cs[131072 + t * 64 + i];
    float x1 = (float)QKV[base + i];
    float x2 = (float)QKV[base + 64 + i];
    float o1 = x1 * c - x2 * s;
    float o2 = x1 * s + x2 * c;
    if (head < 32) { o1 *= QK_SCALE; o2 *= QK_SCALE; }
    QKV[base + i]      = (half_t)o1;
    QKV[base + 64 + i] = (half_t)o2;
  } else {
    int idx = (blockIdx.x - 20480) * 256 + threadIdx.x;   // 8*128*256 = 262144
    int d  = idx & 127;
    int ts = (idx >> 7) & 255;
    int kh = idx >> 15;
    half8 o;
#pragma unroll
    for (int i = 0; i < 8; ++i)
      o[i] = QKV[(size_t)(ts * 8 + i) * QCOLS + HID + NKV * HD + kh * HD + d];
    *(half8*)&Vt[(size_t)kh * (HD * T_SEQ) + (size_t)d * T_SEQ + ts * 8] = o;
  }
}

// ---------------- fp16 GEMM (R3 sync skeleton), B read directly as fp32 ----
// C[M][N] = A[M][K] * B[N][K]^T.  A: fp16 via global_load_lds (pre-swizzled
// source). B: fp32 rows from Bq/Bk/Bv (concat split at 4096/5120).
// R14 fix: B register-loads issued at ph0 (3 phases before the ph3
// cvt+ds_write consumes them) so the pre-write vmcnt wait is ~free.
// Sync structure identical to the verified R3/R8 kernel.
template <int BM, int BN, int OUT_HALF>
__global__ __launch_bounds__(512, 2) void gemm8p_k(const half_t* __restrict__ A,
                                                   const float* __restrict__ Bq,
                                                   const float* __restrict__ Bk,
                                                   const float* __restrict__ Bv,
                                                   void* __restrict__ Cout,
                                                   int M, int N, int K) {
  constexpr int MF = BM / 32;   // per-wave m fragments
  constexpr int NF = BN / 64;   // per-wave n fragments
  constexpr int MH = MF / 2;    // m frags per phase
  constexpr int LA = BM / 64;   // A staging loads/thread per tile
  constexpr int LB = BN / 64;   // B loads/thread per tile
  __shared__ half_t Al[2][BM * 64];
  __shared__ half_t Bl[2][BN * 64];

  const int nbm = M / BM;
  const int nwg = nbm * (N / BN);     // 256 for both instantiations
  const int bid = blockIdx.x;
  const int swz = (bid & 7) * (nwg >> 3) + (bid >> 3);  // bijective XCD swizzle
  const int brow = (swz % nbm) * BM;
  const int bcol = (swz / nbm) * BN;
  const int tid = threadIdx.x;
  const int lane = tid & 63, wid = tid >> 6;
  const int wr = wid >> 2, wc = wid & 3;
  const int lr = lane & 15, hi = lane >> 4;
  const int wrow = wr * (MF * 16), wcol = wc * (NF * 16);

  const half_t* Ab = A + (size_t)brow * K;

  // per-thread B source pointers (row + swizzle constant across K-tiles)
  const float* bp[LB];
#pragma unroll
  for (int l = 0; l < LB; ++l) {
    int c = l * 512 + tid, r = c >> 3, s = c & 7;
    int row = bcol + r;
    const float* src = (row < 4096) ? (Bq + (size_t)row * K)
                     : (row < 5120) ? (Bk + (size_t)(row - 4096) * K)
                                    : (Bv + (size_t)(row - 5120) * K);
    bp[l] = src + ((s ^ (r & 7)) * 8);
  }

  f32x4 acc[MF][NF] = {};
  half8 afr[MH], bfr[NF];
  f32x4 breg[LB][2];

#define STAGE_A(l, k0, buf) { \
    int c_ = (l) * 512 + tid; int r_ = c_ >> 3, s_ = c_ & 7; \
    __builtin_amdgcn_global_load_lds( \
      (cg_void*)(Ab + (size_t)r_ * K + (k0) + ((s_ ^ (r_ & 7)) * 8)), \
      (lds_void*)(&Al[buf][((l) * 512 + wid * 64) * 8]), 16, 0, 0); }
#define LOAD_B_ALL(k0) { \
    _Pragma("unroll") for (int l_ = 0; l_ < LB; ++l_) { \
      breg[l_][0] = *(const f32x4*)(bp[l_] + (k0)); \
      breg[l_][1] = *(const f32x4*)(bp[l_] + (k0) + 4); } }
#define WRITE_B_ALL(buf) { \
    _Pragma("unroll") for (int l_ = 0; l_ < LB; ++l_) { \
      half8 h_; \
      _Pragma("unroll") for (int e_ = 0; e_ < 4; ++e_) { \
        h_[e_] = (half_t)breg[l_][0][e_]; h_[4 + e_] = (half_t)breg[l_][1][e_]; } \
      *(half8*)&Bl[buf][((l_) * 512 + tid) * 8] = h_; } }
#define RD_A(i, mh, kk, buf) { \
    int row_ = wrow + ((mh) * MH + (i)) * 16 + lr; int ks_ = (kk) * 4 + hi; \
    afr[i] = *(const half8*)&Al[buf][row_ * 64 + ((ks_ ^ (row_ & 7)) * 8)]; }
#define RD_B(n, kk, buf) { \
    int row_ = wcol + (n) * 16 + lr; int ks_ = (kk) * 4 + hi; \
    bfr[n] = *(const half8*)&Bl[buf][row_ * 64 + ((ks_ ^ (row_ & 7)) * 8)]; }
#define MFMA_PH(mh) { \
    __builtin_amdgcn_s_setprio(1); \
    _Pragma("unroll") for (int i_ = 0; i_ < MH; ++i_) \
      _Pragma("unroll") for (int n_ = 0; n_ < NF; ++n_) \
        acc[(mh) * MH + i_][n_] = __builtin_amdgcn_mfma_f32_16x16x32_f16( \
            afr[i_], bfr[n_], acc[(mh) * MH + i_][n_], 0, 0, 0); \
    __builtin_amdgcn_s_setprio(0); }

#define DO_TILE(T, BUF) { \
    const int kn_ = ((T) + 1) * 64; const bool pf_ = ((T) + 1) < NT; \
    /* ph0: stage next-A + issue next-B reg loads (3 phases to land) */ \
    if (pf_) { \
      _Pragma("unroll") for (int l_ = 0; l_ < LA; ++l_) STAGE_A(l_, kn_, (BUF) ^ 1); \
      LOAD_B_ALL(kn_); \
    } \
    _Pragma("unroll") for (int n_ = 0; n_ < NF; ++n_) RD_B(n_, 0, BUF); \
    _Pragma("unroll") for (int i_ = 0; i_ < MH; ++i_) RD_A(i_, 0, 0, BUF); \
    MFMA_PH(0); \
    __builtin_amdgcn_s_barrier(); __builtin_amdgcn_sched_barrier(0); \
    /* ph1 */ \
    _Pragma("unroll") for (int i_ = 0; i_ < MH; ++i_) RD_A(i_, 1, 0, BUF); \
    MFMA_PH(1); \
    __builtin_amdgcn_s_barrier(); __builtin_amdgcn_sched_barrier(0); \
    /* ph2 */ \
    _Pragma("unroll") for (int n_ = 0; n_ < NF; ++n_) RD_B(n_, 1, BUF); \
    _Pragma("unroll") for (int i_ = 0; i_ < MH; ++i_) RD_A(i_, 1, 1, BUF); \
    MFMA_PH(1); \
    __builtin_amdgcn_s_barrier(); __builtin_amdgcn_sched_barrier(0); \
    /* ph3: cvt + ds_write next-B, then drain */ \
    _Pragma("unroll") for (int i_ = 0; i_ < MH; ++i_) RD_A(i_, 0, 1, BUF); \
    MFMA_PH(0); \
    if (pf_) { WRITE_B_ALL((BUF) ^ 1); } \
    asm volatile("s_waitcnt vmcnt(0)" ::: "memory"); \
    __syncthreads(); }

  const int NT = K / 64;
  // prologue: stage tile 0 (A via gload_lds, B via reg+cvt), drain, sync
#pragma unroll
  for (int l_ = 0; l_ < LA; ++l_) STAGE_A(l_, 0, 0);
  LOAD_B_ALL(0);
  WRITE_B_ALL(0);
  asm volatile("s_waitcnt vmcnt(0)" ::: "memory");
  __syncthreads();

  for (int t = 0; t < NT; t += 2) {
    DO_TILE(t, 0);
    DO_TILE(t + 1, 1);
  }

#undef STAGE_A
#undef LOAD_B_ALL
#undef WRITE_B_ALL
#undef RD_A
#undef RD_B
#undef MFMA_PH
#undef DO_TILE

#pragma unroll
  for (int m = 0; m < MF; ++m)
#pragma unroll
    for (int n = 0; n < NF; ++n)
#pragma unroll
      for (int r = 0; r < 4; ++r) {
        int row = brow + wrow + m * 16 + hi * 4 + r;
        int col = bcol + wcol + n * 16 + lr;
        float v = acc[m][n][r];
        if (OUT_HALF) ((half_t*)Cout)[(size_t)row * N + col] = (half_t)v;
        else          ((float*)Cout)[(size_t)row * N + col] = v;
      }
}

// ---------------- fused causal GQA flash attention (R10-verified) ----------
// 4 waves, QBLK=64, 2-phase prefetch, setprio on MFMA clusters, defer-max,
// lane-partial l. Grid 1024 = 32 qb (longest first) x 32 heads.
__global__ __launch_bounds__(256, 2) void attn_k(const half_t* __restrict__ QKV,
                                                 const half_t* __restrict__ Vt,
                                                 half_t* __restrict__ Ob) {
  const int bid = blockIdx.x;
  const int qb = 31 - (bid >> 5);   // longest blocks dispatch first
  const int h  = bid & 31;
  const int kh = h >> 2;
  const int tid = threadIdx.x;
  const int lane = tid & 63;
  const int w = tid >> 6;
  const int lr = lane & 15, hi = lane >> 4;
  const int qrow = qb * 64 + w * 16;

  __shared__ half_t Klds[2][64 * 128];   // [kv][128] swizzled-linear
  __shared__ half_t Vlds[2][128 * 64];   // [d][kv]   swizzled-linear
  __shared__ half_t Plds[4 * 16 * 72];   // per-wave P, padded rows

  const half_t* Qp  = QKV + h * HD;
  const half_t* Kp  = QKV + HID + kh * HD;
  const half_t* Vtp = Vt + (size_t)kh * (HD * T_SEQ);

  half8 qf[4];
#pragma unroll
  for (int kk = 0; kk < 4; ++kk)
    qf[kk] = *(const half8*)&Qp[(size_t)(qrow + lr) * QCOLS + kk * 32 + hi * 8];

  f32x4 acc[8] = {};
  float mrow[4], lrow[4];
#pragma unroll
  for (int r = 0; r < 4; ++r) { mrow[r] = -1e30f; lrow[r] = 0.0f; }

  half_t* Pw = &Plds[w * (16 * 72)];

#define STAGE_KV(kv0, buf) { \
    _Pragma("unroll") for (int c_ = 0; c_ < 4; ++c_) { \
      int chunk_ = c_ * 256 + tid; \
      int r_ = chunk_ >> 4, s_ = chunk_ & 15; \
      int cc_ = (s_ & 8) | ((s_ ^ r_) & 7); \
      __builtin_amdgcn_global_load_lds( \
          (cg_void*)(Kp + (size_t)((kv0) + r_) * QCOLS + cc_ * 8), \
          (lds_void*)(&Klds[buf][(c_ * 256 + w * 64) * 8]), 16, 0, 0); } \
    _Pragma("unroll") for (int c_ = 0; c_ < 4; ++c_) { \
      int chunk_ = c_ * 256 + tid; \
      int r_ = chunk_ >> 3, s_ = chunk_ & 7; \
      int cc_ = (s_ ^ r_) & 7; \
      __builtin_amdgcn_global_load_lds( \
          (cg_void*)(Vtp + (size_t)r_ * T_SEQ + (kv0) + cc_ * 8), \
          (lds_void*)(&Vlds[buf][(c_ * 256 + w * 64) * 8]), 16, 0, 0); } }

#define COMPUTE(T, BUF) { \
    const int kv0_ = (T) * 64; \
    f32x4 sc[4] = {}; \
    __builtin_amdgcn_s_setprio(1); \
    _Pragma("unroll") for (int jt_ = 0; jt_ < 4; ++jt_) \
      _Pragma("unroll") for (int kk_ = 0; kk_ < 4; ++kk_) { \
        int srow_ = jt_ * 16 + lr; \
        int sl_ = kk_ * 4 + hi; \
        int c_ = (sl_ & 8) | ((sl_ ^ srow_) & 7); \
        half8 kf_ = *(const half8*)&Klds[BUF][srow_ * 128 + c_ * 8]; \
        sc[jt_] = __builtin_amdgcn_mfma_f32_16x16x32_f16(qf[kk_], kf_, sc[jt_], 0, 0, 0); \
      } \
    __builtin_amdgcn_s_setprio(0); \
    if ((T) == qb) { \
      _Pragma("unroll") for (int jt_ = 0; jt_ < 4; ++jt_) \
        _Pragma("unroll") for (int r_ = 0; r_ < 4; ++r_) { \
          int ig_ = qrow + hi * 4 + r_; \
          int jg_ = kv0_ + jt_ * 16 + lr; \
          if (jg_ > ig_) sc[jt_][r_] = -1e30f; \
        } \
    } \
    float mx_[4]; \
    _Pragma("unroll") for (int r_ = 0; r_ < 4; ++r_) \
      mx_[r_] = fmaxf(fmaxf(sc[0][r_], sc[1][r_]), fmaxf(sc[2][r_], sc[3][r_])); \
    _Pragma("unroll") for (int off_ = 1; off_ < 16; off_ <<= 1) \
      _Pragma("unroll") for (int r_ = 0; r_ < 4; ++r_) \
        mx_[r_] = fmaxf(mx_[r_], __shfl_xor(mx_[r_], off_, 64)); \
    bool grow_ = false; \
    _Pragma("unroll") for (int r_ = 0; r_ < 4; ++r_) grow_ = grow_ || (mx_[r_] > mrow[r_]); \
    if (__any(grow_)) { \
      float scl_[4]; \
      _Pragma("unroll") for (int r_ = 0; r_ < 4; ++r_) { \
        float mn_ = fmaxf(mrow[r_], mx_[r_]); \
        scl_[r_] = __expf(mrow[r_] - mn_); \
        mrow[r_] = mn_; \
        float ls_ = 0.0f; \
        _Pragma("unroll") for (int jt_ = 0; jt_ < 4; ++jt_) { \
          sc[jt_][r_] = __expf(sc[jt_][r_] - mn_); ls_ += sc[jt_][r_]; } \
        lrow[r_] = lrow[r_] * scl_[r_] + ls_; \
      } \
      _Pragma("unroll") for (int g_ = 0; g_ < 8; ++g_) \
        _Pragma("unroll") for (int r_ = 0; r_ < 4; ++r_) acc[g_][r_] *= scl_[r_]; \
    } else { \
      _Pragma("unroll") for (int r_ = 0; r_ < 4; ++r_) { \
        float ls_ = 0.0f; \
        _Pragma("unroll") for (int jt_ = 0; jt_ < 4; ++jt_) { \
          sc[jt_][r_] = __expf(sc[jt_][r_] - mrow[r_]); ls_ += sc[jt_][r_]; } \
        lrow[r_] += ls_; \
      } \
    } \
    _Pragma("unroll") for (int jt_ = 0; jt_ < 4; ++jt_) \
      _Pragma("unroll") for (int r_ = 0; r_ < 4; ++r_) \
        Pw[(hi * 4 + r_) * 72 + jt_ * 16 + lr] = (half_t)sc[jt_][r_]; \
    half8 pf0_ = *(const half8*)&Pw[lr * 72 + hi * 8]; \
    half8 pf1_ = *(const half8*)&Pw[lr * 72 + 32 + hi * 8]; \
    __builtin_amdgcn_s_setprio(1); \
    _Pragma("unroll") for (int g_ = 0; g_ < 8; ++g_) { \
      int vrow_ = g_ * 16 + lr; \
      { int c0_ = (hi ^ vrow_) & 7; \
        half8 vf_ = *(const half8*)&Vlds[BUF][vrow_ * 64 + c0_ * 8]; \
        acc[g_] = __builtin_amdgcn_mfma_f32_16x16x32_f16(pf0_, vf_, acc[g_], 0, 0, 0); } \
      { int c1_ = ((4 + hi) ^ vrow_) & 7; \
        half8 vf_ = *(const half8*)&Vlds[BUF][vrow_ * 64 + c1_ * 8]; \
        acc[g_] = __builtin_amdgcn_mfma_f32_16x16x32_f16(pf1_, vf_, acc[g_], 0, 0, 0); } \
    } \
    __builtin_amdgcn_s_setprio(0); }

#define TILE_SYNC() { asm volatile("s_waitcnt vmcnt(0)" ::: "memory"); \
                      __builtin_amdgcn_s_barrier(); __builtin_amdgcn_sched_barrier(0); }

  const int nt = qb + 1;
  STAGE_KV(0, 0);
  TILE_SYNC();

  int t = 0;
  for (; t + 2 <= nt; t += 2) {
    STAGE_KV((t + 1) * 64, 1);
    COMPUTE(t, 0);
    TILE_SYNC();
    if (t + 2 < nt) { STAGE_KV((t + 2) * 64, 0); }
    COMPUTE(t + 1, 1);
    TILE_SYNC();
  }
  if (t < nt) { COMPUTE(t, 0); }

#undef STAGE_KV
#undef COMPUTE
#undef TILE_SYNC

  float linv[4];
#pragma unroll
  for (int r = 0; r < 4; ++r) {
    float l = lrow[r];
#pragma unroll
    for (int off = 1; off < 16; off <<= 1) l += __shfl_xor(l, off, 64);
    linv[r] = 1.0f / l;
  }
#pragma unroll
  for (int g = 0; g < 8; ++g)
#pragma unroll
    for (int r = 0; r < 4; ++r) {
      int row = qrow + hi * 4 + r;
      int col = h * HD + g * 16 + lr;
      Ob[(size_t)row * HID + col] = (half_t)(acc[g][r] * linv[r]);
    }
}

// ---------------- launch ----------------
extern "C" void kernel_launch(void* const* d_in, const int* in_sizes, int n_in,
                              void* d_out, int out_size, void* d_ws, size_t ws_size,
                              hipStream_t stream) {
  const float* hs = (const float*)d_in[0];
  const float* Wq = (const float*)d_in[1];
  const float* Wk = (const float*)d_in[2];
  const float* Wv = (const float*)d_in[3];
  const float* Wo = (const float*)d_in[4];
  float* out = (float*)d_out;

  char* ws = (char*)d_ws;
  half_t* Xh    = (half_t*)(ws + 0);           // 16 MB (dead after gemm1)
  half_t* Vt    = (half_t*)(ws + 0);           // 4 MB, reuses Xh region
  half_t* QKV   = (half_t*)(ws + 100663296);   // 24 MB [2048][6144]
  half_t* attnh = (half_t*)(ws + 125829120);   // 16 MB [2048][4096]
  float*  cs    = (float*)(ws + 142606336);    // 1 MB cos|sin tables
  if (ws_size < 143654912ull) return;

  cast_x_k<<<8192, 256, 0, stream>>>(hs, Xh);
  rope_tables_k<<<512, 256, 0, stream>>>(cs);

  gemm8p_k<256, 192, 1><<<256, 512, 0, stream>>>(Xh, Wq, Wk, Wv, (void*)QKV, 2048, 6144, 4096);
  rope_vt_k<<<21504, 256, 0, stream>>>(QKV, cs, Vt);
  attn_k<<<1024, 256, 0, stream>>>(QKV, Vt, attnh);
  gemm8p_k<256, 128, 0><<<256, 512, 0, stream>>>(attnh, Wo, Wo, Wo, (void*)out, 2048, 4096, 4096);
}

// Round 15
// 313.129 us; speedup vs baseline: 1.1104x; 1.1104x over previous
//
#include <hip/hip_runtime.h>
#include <stdint.h>

#define T_SEQ   2048
#define HID     4096
#define NH      32
#define NKV     8
#define HD      128
#define QCOLS   6144
#define QK_SCALE 0.08838834764831845f  // 1/sqrt(128)

typedef _Float16 half_t;
typedef _Float16 half8 __attribute__((ext_vector_type(8)));
typedef _Float16 half4v __attribute__((ext_vector_type(4)));
typedef float    f32x4 __attribute__((ext_vector_type(4)));

typedef __attribute__((address_space(1))) const void cg_void;
typedef __attribute__((address_space(3))) void lds_void;

// ---------------- cast fp32 -> fp16 for X only (weights read fp32 by GEMM) --
__global__ __launch_bounds__(256) void cast_x_k(const float* __restrict__ X,
                                                half_t* __restrict__ Xh) {
  int i = blockIdx.x * 256 + threadIdx.x;   // float4 index, total 2097152
  f32x4 v = *(const f32x4*)(X + (size_t)i * 4);
  half4v o;
  o[0] = (half_t)v[0]; o[1] = (half_t)v[1]; o[2] = (half_t)v[2]; o[3] = (half_t)v[3];
  *(half4v*)(Xh + (size_t)i * 4) = o;
}

// ---------------- RoPE cos/sin tables ----------------
__global__ __launch_bounds__(256) void rope_tables_k(float* __restrict__ cs) {
  int idx = blockIdx.x * 256 + threadIdx.x;  // 2048*64
  int t = idx >> 6, i = idx & 63;
  float inv = expf(-(float)i * 0.14391156831212787f);
  float a = (float)t * inv;
  cs[idx] = cosf(a);
  cs[131072 + idx] = sinf(a);
}

// ---------- fused: RoPE apply (blocks < 20480) + V transpose (rest) ----------
__global__ __launch_bounds__(256) void rope_vt_k(half_t* __restrict__ QKV,
                                                 const float* __restrict__ cs,
                                                 half_t* __restrict__ Vt) {
  if (blockIdx.x < 20480) {
    int idx = blockIdx.x * 256 + threadIdx.x;  // 2048*40*64
    int i = idx & 63;
    int rem = idx >> 6;
    int head = rem % 40;
    int t = rem / 40;
    int colbase = (head < 32) ? head * HD : HID + (head - 32) * HD;
    size_t base = (size_t)t * QCOLS + colbase;
    float c = cs[t * 64 + i], s = cs[131072 + t * 64 + i];
    float x1 = (float)QKV[base + i];
    float x2 = (float)QKV[base + 64 + i];
    float o1 = x1 * c - x2 * s;
    float o2 = x1 * s + x2 * c;
    if (head < 32) { o1 *= QK_SCALE; o2 *= QK_SCALE; }
    QKV[base + i]      = (half_t)o1;
    QKV[base + 64 + i] = (half_t)o2;
  } else {
    int idx = (blockIdx.x - 20480) * 256 + threadIdx.x;   // 8*128*256 = 262144
    int d  = idx & 127;
    int ts = (idx >> 7) & 255;
    int kh = idx >> 15;
    half8 o;
#pragma unroll
    for (int i = 0; i < 8; ++i)
      o[i] = QKV[(size_t)(ts * 8 + i) * QCOLS + HID + NKV * HD + kh * HD + d];
    *(half8*)&Vt[(size_t)kh * (HD * T_SEQ) + (size_t)d * T_SEQ + ts * 8] = o;
  }
}

// ---------------- fp16 GEMM (R13-verified): B read directly as fp32 --------
// C[M][N] = A[M][K] * B[N][K]^T.  A: fp16 via global_load_lds (pre-swizzled
// source). B: fp32 rows from Bq/Bk/Bv (concat split at 4096/5120), loaded to
// regs at ph1, converted + ds_write'd at ph3 inside the existing drain
// region. Sync structure identical to the verified R3/R8 kernel.
template <int BM, int BN, int OUT_HALF>
__global__ __launch_bounds__(512, 2) void gemm8p_k(const half_t* __restrict__ A,
                                                   const float* __restrict__ Bq,
                                                   const float* __restrict__ Bk,
                                                   const float* __restrict__ Bv,
                                                   void* __restrict__ Cout,
                                                   int M, int N, int K) {
  constexpr int MF = BM / 32;   // per-wave m fragments
  constexpr int NF = BN / 64;   // per-wave n fragments
  constexpr int MH = MF / 2;    // m frags per phase
  constexpr int LA = BM / 64;   // A staging loads/thread per tile
  constexpr int LB = BN / 64;   // B loads/thread per tile
  __shared__ half_t Al[2][BM * 64];
  __shared__ half_t Bl[2][BN * 64];

  const int nbm = M / BM;
  const int nwg = nbm * (N / BN);     // 256 for both instantiations
  const int bid = blockIdx.x;
  const int swz = (bid & 7) * (nwg >> 3) + (bid >> 3);  // bijective XCD swizzle
  const int brow = (swz % nbm) * BM;
  const int bcol = (swz / nbm) * BN;
  const int tid = threadIdx.x;
  const int lane = tid & 63, wid = tid >> 6;
  const int wr = wid >> 2, wc = wid & 3;
  const int lr = lane & 15, hi = lane >> 4;
  const int wrow = wr * (MF * 16), wcol = wc * (NF * 16);

  const half_t* Ab = A + (size_t)brow * K;

  // per-thread B source pointers (row + swizzle constant across K-tiles)
  const float* bp[LB];
#pragma unroll
  for (int l = 0; l < LB; ++l) {
    int c = l * 512 + tid, r = c >> 3, s = c & 7;
    int row = bcol + r;
    const float* src = (row < 4096) ? (Bq + (size_t)row * K)
                     : (row < 5120) ? (Bk + (size_t)(row - 4096) * K)
                                    : (Bv + (size_t)(row - 5120) * K);
    bp[l] = src + ((s ^ (r & 7)) * 8);
  }

  f32x4 acc[MF][NF] = {};
  half8 afr[MH], bfr[NF];
  f32x4 breg[LB][2];

#define STAGE_A(l, k0, buf) { \
    int c_ = (l) * 512 + tid; int r_ = c_ >> 3, s_ = c_ & 7; \
    __builtin_amdgcn_global_load_lds( \
      (cg_void*)(Ab + (size_t)r_ * K + (k0) + ((s_ ^ (r_ & 7)) * 8)), \
      (lds_void*)(&Al[buf][((l) * 512 + wid * 64) * 8]), 16, 0, 0); }
#define LOAD_B_ALL(k0) { \
    _Pragma("unroll") for (int l_ = 0; l_ < LB; ++l_) { \
      breg[l_][0] = *(const f32x4*)(bp[l_] + (k0)); \
      breg[l_][1] = *(const f32x4*)(bp[l_] + (k0) + 4); } }
#define WRITE_B_ALL(buf) { \
    _Pragma("unroll") for (int l_ = 0; l_ < LB; ++l_) { \
      half8 h_; \
      _Pragma("unroll") for (int e_ = 0; e_ < 4; ++e_) { \
        h_[e_] = (half_t)breg[l_][0][e_]; h_[4 + e_] = (half_t)breg[l_][1][e_]; } \
      *(half8*)&Bl[buf][((l_) * 512 + tid) * 8] = h_; } }
#define RD_A(i, mh, kk, buf) { \
    int row_ = wrow + ((mh) * MH + (i)) * 16 + lr; int ks_ = (kk) * 4 + hi; \
    afr[i] = *(const half8*)&Al[buf][row_ * 64 + ((ks_ ^ (row_ & 7)) * 8)]; }
#define RD_B(n, kk, buf) { \
    int row_ = wcol + (n) * 16 + lr; int ks_ = (kk) * 4 + hi; \
    bfr[n] = *(const half8*)&Bl[buf][row_ * 64 + ((ks_ ^ (row_ & 7)) * 8)]; }
#define MFMA_PH(mh) { \
    __builtin_amdgcn_s_setprio(1); \
    _Pragma("unroll") for (int i_ = 0; i_ < MH; ++i_) \
      _Pragma("unroll") for (int n_ = 0; n_ < NF; ++n_) \
        acc[(mh) * MH + i_][n_] = __builtin_amdgcn_mfma_f32_16x16x32_f16( \
            afr[i_], bfr[n_], acc[(mh) * MH + i_][n_], 0, 0, 0); \
    __builtin_amdgcn_s_setprio(0); }

#define DO_TILE(T, BUF) { \
    const int kn_ = ((T) + 1) * 64; const bool pf_ = ((T) + 1) < NT; \
    if (pf_) { _Pragma("unroll") for (int l_ = 0; l_ < LA; ++l_) STAGE_A(l_, kn_, (BUF) ^ 1); } \
    _Pragma("unroll") for (int n_ = 0; n_ < NF; ++n_) RD_B(n_, 0, BUF); \
    _Pragma("unroll") for (int i_ = 0; i_ < MH; ++i_) RD_A(i_, 0, 0, BUF); \
    MFMA_PH(0); \
    __builtin_amdgcn_s_barrier(); __builtin_amdgcn_sched_barrier(0); \
    if (pf_) { LOAD_B_ALL(kn_); } \
    _Pragma("unroll") for (int i_ = 0; i_ < MH; ++i_) RD_A(i_, 1, 0, BUF); \
    MFMA_PH(1); \
    __builtin_amdgcn_s_barrier(); __builtin_amdgcn_sched_barrier(0); \
    _Pragma("unroll") for (int n_ = 0; n_ < NF; ++n_) RD_B(n_, 1, BUF); \
    _Pragma("unroll") for (int i_ = 0; i_ < MH; ++i_) RD_A(i_, 1, 1, BUF); \
    MFMA_PH(1); \
    __builtin_amdgcn_s_barrier(); __builtin_amdgcn_sched_barrier(0); \
    _Pragma("unroll") for (int i_ = 0; i_ < MH; ++i_) RD_A(i_, 0, 1, BUF); \
    MFMA_PH(0); \
    if (pf_) { WRITE_B_ALL((BUF) ^ 1); } \
    asm volatile("s_waitcnt vmcnt(0)" ::: "memory"); \
    __syncthreads(); }

  const int NT = K / 64;
  // prologue: stage tile 0 (A via gload_lds, B via reg+cvt), drain, sync
#pragma unroll
  for (int l_ = 0; l_ < LA; ++l_) STAGE_A(l_, 0, 0);
  LOAD_B_ALL(0);
  WRITE_B_ALL(0);
  asm volatile("s_waitcnt vmcnt(0)" ::: "memory");
  __syncthreads();

  for (int t = 0; t < NT; t += 2) {
    DO_TILE(t, 0);
    DO_TILE(t + 1, 1);
  }

#undef STAGE_A
#undef LOAD_B_ALL
#undef WRITE_B_ALL
#undef RD_A
#undef RD_B
#undef MFMA_PH
#undef DO_TILE

#pragma unroll
  for (int m = 0; m < MF; ++m)
#pragma unroll
    for (int n = 0; n < NF; ++n)
#pragma unroll
      for (int r = 0; r < 4; ++r) {
        int row = brow + wrow + m * 16 + hi * 4 + r;
        int col = bcol + wcol + n * 16 + lr;
        float v = acc[m][n][r];
        if (OUT_HALF) ((half_t*)Cout)[(size_t)row * N + col] = (half_t)v;
        else          ((float*)Cout)[(size_t)row * N + col] = v;
      }
}

// ---------------- fused causal GQA flash attention (R10 + THR=8 defer-max) --
// 4 waves, QBLK=64, 2-phase prefetch, setprio on MFMA clusters, lane-partial
// l. T13: skip O-rescale while max growth <= 8 (P bounded by e^8; l, acc in
// fp32 -- no overflow; epilogue division cancels the scale).
__global__ __launch_bounds__(256, 2) void attn_k(const half_t* __restrict__ QKV,
                                                 const half_t* __restrict__ Vt,
                                                 half_t* __restrict__ Ob) {
  const int bid = blockIdx.x;
  const int qb = 31 - (bid >> 5);   // longest blocks dispatch first
  const int h  = bid & 31;
  const int kh = h >> 2;
  const int tid = threadIdx.x;
  const int lane = tid & 63;
  const int w = tid >> 6;
  const int lr = lane & 15, hi = lane >> 4;
  const int qrow = qb * 64 + w * 16;

  __shared__ half_t Klds[2][64 * 128];   // [kv][128] swizzled-linear
  __shared__ half_t Vlds[2][128 * 64];   // [d][kv]   swizzled-linear
  __shared__ half_t Plds[4 * 16 * 72];   // per-wave P, padded rows

  const half_t* Qp  = QKV + h * HD;
  const half_t* Kp  = QKV + HID + kh * HD;
  const half_t* Vtp = Vt + (size_t)kh * (HD * T_SEQ);

  half8 qf[4];
#pragma unroll
  for (int kk = 0; kk < 4; ++kk)
    qf[kk] = *(const half8*)&Qp[(size_t)(qrow + lr) * QCOLS + kk * 32 + hi * 8];

  f32x4 acc[8] = {};
  float mrow[4], lrow[4];
#pragma unroll
  for (int r = 0; r < 4; ++r) { mrow[r] = -1e30f; lrow[r] = 0.0f; }

  half_t* Pw = &Plds[w * (16 * 72)];

#define STAGE_KV(kv0, buf) { \
    _Pragma("unroll") for (int c_ = 0; c_ < 4; ++c_) { \
      int chunk_ = c_ * 256 + tid; \
      int r_ = chunk_ >> 4, s_ = chunk_ & 15; \
      int cc_ = (s_ & 8) | ((s_ ^ r_) & 7); \
      __builtin_amdgcn_global_load_lds( \
          (cg_void*)(Kp + (size_t)((kv0) + r_) * QCOLS + cc_ * 8), \
          (lds_void*)(&Klds[buf][(c_ * 256 + w * 64) * 8]), 16, 0, 0); } \
    _Pragma("unroll") for (int c_ = 0; c_ < 4; ++c_) { \
      int chunk_ = c_ * 256 + tid; \
      int r_ = chunk_ >> 3, s_ = chunk_ & 7; \
      int cc_ = (s_ ^ r_) & 7; \
      __builtin_amdgcn_global_load_lds( \
          (cg_void*)(Vtp + (size_t)r_ * T_SEQ + (kv0) + cc_ * 8), \
          (lds_void*)(&Vlds[buf][(c_ * 256 + w * 64) * 8]), 16, 0, 0); } }

#define COMPUTE(T, BUF) { \
    const int kv0_ = (T) * 64; \
    f32x4 sc[4] = {}; \
    __builtin_amdgcn_s_setprio(1); \
    _Pragma("unroll") for (int jt_ = 0; jt_ < 4; ++jt_) \
      _Pragma("unroll") for (int kk_ = 0; kk_ < 4; ++kk_) { \
        int srow_ = jt_ * 16 + lr; \
        int sl_ = kk_ * 4 + hi; \
        int c_ = (sl_ & 8) | ((sl_ ^ srow_) & 7); \
        half8 kf_ = *(const half8*)&Klds[BUF][srow_ * 128 + c_ * 8]; \
        sc[jt_] = __builtin_amdgcn_mfma_f32_16x16x32_f16(qf[kk_], kf_, sc[jt_], 0, 0, 0); \
      } \
    __builtin_amdgcn_s_setprio(0); \
    if ((T) == qb) { \
      _Pragma("unroll") for (int jt_ = 0; jt_ < 4; ++jt_) \
        _Pragma("unroll") for (int r_ = 0; r_ < 4; ++r_) { \
          int ig_ = qrow + hi * 4 + r_; \
          int jg_ = kv0_ + jt_ * 16 + lr; \
          if (jg_ > ig_) sc[jt_][r_] = -1e30f; \
        } \
    } \
    float mx_[4]; \
    _Pragma("unroll") for (int r_ = 0; r_ < 4; ++r_) \
      mx_[r_] = fmaxf(fmaxf(sc[0][r_], sc[1][r_]), fmaxf(sc[2][r_], sc[3][r_])); \
    _Pragma("unroll") for (int off_ = 1; off_ < 16; off_ <<= 1) \
      _Pragma("unroll") for (int r_ = 0; r_ < 4; ++r_) \
        mx_[r_] = fmaxf(mx_[r_], __shfl_xor(mx_[r_], off_, 64)); \
    bool grow_ = false; \
    _Pragma("unroll") for (int r_ = 0; r_ < 4; ++r_) grow_ = grow_ || (mx_[r_] > mrow[r_] + 8.0f); \
    if (__any(grow_)) { \
      float scl_[4]; \
      _Pragma("unroll") for (int r_ = 0; r_ < 4; ++r_) { \
        float mn_ = fmaxf(mrow[r_], mx_[r_]); \
        scl_[r_] = __expf(mrow[r_] - mn_); \
        mrow[r_] = mn_; \
        float ls_ = 0.0f; \
        _Pragma("unroll") for (int jt_ = 0; jt_ < 4; ++jt_) { \
          sc[jt_][r_] = __expf(sc[jt_][r_] - mn_); ls_ += sc[jt_][r_]; } \
        lrow[r_] = lrow[r_] * scl_[r_] + ls_; \
      } \
      _Pragma("unroll") for (int g_ = 0; g_ < 8; ++g_) \
        _Pragma("unroll") for (int r_ = 0; r_ < 4; ++r_) acc[g_][r_] *= scl_[r_]; \
    } else { \
      _Pragma("unroll") for (int r_ = 0; r_ < 4; ++r_) { \
        float ls_ = 0.0f; \
        _Pragma("unroll") for (int jt_ = 0; jt_ < 4; ++jt_) { \
          sc[jt_][r_] = __expf(sc[jt_][r_] - mrow[r_]); ls_ += sc[jt_][r_]; } \
        lrow[r_] += ls_; \
      } \
    } \
    _Pragma("unroll") for (int jt_ = 0; jt_ < 4; ++jt_) \
      _Pragma("unroll") for (int r_ = 0; r_ < 4; ++r_) \
        Pw[(hi * 4 + r_) * 72 + jt_ * 16 + lr] = (half_t)sc[jt_][r_]; \
    half8 pf0_ = *(const half8*)&Pw[lr * 72 + hi * 8]; \
    half8 pf1_ = *(const half8*)&Pw[lr * 72 + 32 + hi * 8]; \
    __builtin_amdgcn_s_setprio(1); \
    _Pragma("unroll") for (int g_ = 0; g_ < 8; ++g_) { \
      int vrow_ = g_ * 16 + lr; \
      { int c0_ = (hi ^ vrow_) & 7; \
        half8 vf_ = *(const half8*)&Vlds[BUF][vrow_ * 64 + c0_ * 8]; \
        acc[g_] = __builtin_amdgcn_mfma_f32_16x16x32_f16(pf0_, vf_, acc[g_], 0, 0, 0); } \
      { int c1_ = ((4 + hi) ^ vrow_) & 7; \
        half8 vf_ = *(const half8*)&Vlds[BUF][vrow_ * 64 + c1_ * 8]; \
        acc[g_] = __builtin_amdgcn_mfma_f32_16x16x32_f16(pf1_, vf_, acc[g_], 0, 0, 0); } \
    } \
    __builtin_amdgcn_s_setprio(0); }

#define TILE_SYNC() { asm volatile("s_waitcnt vmcnt(0)" ::: "memory"); \
                      __builtin_amdgcn_s_barrier(); __builtin_amdgcn_sched_barrier(0); }

  const int nt = qb + 1;
  STAGE_KV(0, 0);
  TILE_SYNC();

  int t = 0;
  for (; t + 2 <= nt; t += 2) {
    STAGE_KV((t + 1) * 64, 1);
    COMPUTE(t, 0);
    TILE_SYNC();
    if (t + 2 < nt) { STAGE_KV((t + 2) * 64, 0); }
    COMPUTE(t + 1, 1);
    TILE_SYNC();
  }
  if (t < nt) { COMPUTE(t, 0); }

#undef STAGE_KV
#undef COMPUTE
#undef TILE_SYNC

  float linv[4];
#pragma unroll
  for (int r = 0; r < 4; ++r) {
    float l = lrow[r];
#pragma unroll
    for (int off = 1; off < 16; off <<= 1) l += __shfl_xor(l, off, 64);
    linv[r] = 1.0f / l;
  }
#pragma unroll
  for (int g = 0; g < 8; ++g)
#pragma unroll
    for (int r = 0; r < 4; ++r) {
      int row = qrow + hi * 4 + r;
      int col = h * HD + g * 16 + lr;
      Ob[(size_t)row * HID + col] = (half_t)(acc[g][r] * linv[r]);
    }
}

// ---------------- launch ----------------
extern "C" void kernel_launch(void* const* d_in, const int* in_sizes, int n_in,
                              void* d_out, int out_size, void* d_ws, size_t ws_size,
                              hipStream_t stream) {
  const float* hs = (const float*)d_in[0];
  const float* Wq = (const float*)d_in[1];
  const float* Wk = (const float*)d_in[2];
  const float* Wv = (const float*)d_in[3];
  const float* Wo = (const float*)d_in[4];
  float* out = (float*)d_out;

  char* ws = (char*)d_ws;
  half_t* Xh    = (half_t*)(ws + 0);           // 16 MB (dead after gemm1)
  half_t* Vt    = (half_t*)(ws + 0);           // 4 MB, reuses Xh region
  half_t* QKV   = (half_t*)(ws + 100663296);   // 24 MB [2048][6144]
  half_t* attnh = (half_t*)(ws + 125829120);   // 16 MB [2048][4096]
  float*  cs    = (float*)(ws + 142606336);    // 1 MB cos|sin tables
  if (ws_size < 143654912ull) return;

  cast_x_k<<<8192, 256, 0, stream>>>(hs, Xh);
  rope_tables_k<<<512, 256, 0, stream>>>(cs);

  gemm8p_k<256, 192, 1><<<256, 512, 0, stream>>>(Xh, Wq, Wk, Wv, (void*)QKV, 2048, 6144, 4096);
  rope_vt_k<<<21504, 256, 0, stream>>>(QKV, cs, Vt);
  attn_k<<<1024, 256, 0, stream>>>(QKV, Vt, attnh);
  gemm8p_k<256, 128, 0><<<256, 512, 0, stream>>>(attnh, Wo, Wo, Wo, (void*)out, 2048, 4096, 4096);
}

// Round 17
// 304.676 us; speedup vs baseline: 1.1412x; 1.0277x over previous
//
#include <hip/hip_runtime.h>
#include <stdint.h>

#define T_SEQ   2048
#define HID     4096
#define NH      32
#define NKV     8
#define HD      128
#define QCOLS   6144
#define QK_SCALE 0.08838834764831845f  // 1/sqrt(128)

typedef _Float16 half_t;
typedef _Float16 half8 __attribute__((ext_vector_type(8)));
typedef _Float16 half4v __attribute__((ext_vector_type(4)));
typedef __fp16   fp16x2 __attribute__((ext_vector_type(2)));
typedef float    f32x4 __attribute__((ext_vector_type(4)));

typedef __attribute__((address_space(1))) const void cg_void;
typedef __attribute__((address_space(3))) void lds_void;

typedef union { uint32_t u[4]; half8 h; } pfu;

static __device__ __forceinline__ uint32_t pkrtz(float a, float b) {
  union { fp16x2 h; uint32_t u; } c;
  c.h = __builtin_amdgcn_cvt_pkrtz(a, b);
  return c.u;
}

// ---------------- cast fp32 -> fp16 for X only (weights read fp32 by GEMM) --
__global__ __launch_bounds__(256) void cast_x_k(const float* __restrict__ X,
                                                half_t* __restrict__ Xh) {
  int i = blockIdx.x * 256 + threadIdx.x;   // float4 index, total 2097152
  f32x4 v = *(const f32x4*)(X + (size_t)i * 4);
  half4v o;
  o[0] = (half_t)v[0]; o[1] = (half_t)v[1]; o[2] = (half_t)v[2]; o[3] = (half_t)v[3];
  *(half4v*)(Xh + (size_t)i * 4) = o;
}

// ---------------- RoPE cos/sin tables ----------------
__global__ __launch_bounds__(256) void rope_tables_k(float* __restrict__ cs) {
  int idx = blockIdx.x * 256 + threadIdx.x;  // 2048*64
  int t = idx >> 6, i = idx & 63;
  float inv = expf(-(float)i * 0.14391156831212787f);
  float a = (float)t * inv;
  cs[idx] = cosf(a);
  cs[131072 + idx] = sinf(a);
}

// ---------- fused: RoPE apply (blocks < 20480) + V transpose (rest) ----------
__global__ __launch_bounds__(256) void rope_vt_k(half_t* __restrict__ QKV,
                                                 const float* __restrict__ cs,
                                                 half_t* __restrict__ Vt) {
  if (blockIdx.x < 20480) {
    int idx = blockIdx.x * 256 + threadIdx.x;  // 2048*40*64
    int i = idx & 63;
    int rem = idx >> 6;
    int head = rem % 40;
    int t = rem / 40;
    int colbase = (head < 32) ? head * HD : HID + (head - 32) * HD;
    size_t base = (size_t)t * QCOLS + colbase;
    float c = cs[t * 64 + i], s = cs[131072 + t * 64 + i];
    float x1 = (float)QKV[base + i];
    float x2 = (float)QKV[base + 64 + i];
    float o1 = x1 * c - x2 * s;
    float o2 = x1 * s + x2 * c;
    if (head < 32) { o1 *= QK_SCALE; o2 *= QK_SCALE; }
    QKV[base + i]      = (half_t)o1;
    QKV[base + 64 + i] = (half_t)o2;
  } else {
    int idx = (blockIdx.x - 20480) * 256 + threadIdx.x;   // 8*128*256 = 262144
    int d  = idx & 127;
    int ts = (idx >> 7) & 255;
    int kh = idx >> 15;
    half8 o;
#pragma unroll
    for (int i = 0; i < 8; ++i)
      o[i] = QKV[(size_t)(ts * 8 + i) * QCOLS + HID + NKV * HD + kh * HD + d];
    *(half8*)&Vt[(size_t)kh * (HD * T_SEQ) + (size_t)d * T_SEQ + ts * 8] = o;
  }
}

// ---------------- fp16 GEMM (R13-verified): B read directly as fp32 --------
template <int BM, int BN, int OUT_HALF>
__global__ __launch_bounds__(512, 2) void gemm8p_k(const half_t* __restrict__ A,
                                                   const float* __restrict__ Bq,
                                                   const float* __restrict__ Bk,
                                                   const float* __restrict__ Bv,
                                                   void* __restrict__ Cout,
                                                   int M, int N, int K) {
  constexpr int MF = BM / 32;   // per-wave m fragments
  constexpr int NF = BN / 64;   // per-wave n fragments
  constexpr int MH = MF / 2;    // m frags per phase
  constexpr int LA = BM / 64;   // A staging loads/thread per tile
  constexpr int LB = BN / 64;   // B loads/thread per tile
  __shared__ half_t Al[2][BM * 64];
  __shared__ half_t Bl[2][BN * 64];

  const int nbm = M / BM;
  const int nwg = nbm * (N / BN);     // 256 for both instantiations
  const int bid = blockIdx.x;
  const int swz = (bid & 7) * (nwg >> 3) + (bid >> 3);  // bijective XCD swizzle
  const int brow = (swz % nbm) * BM;
  const int bcol = (swz / nbm) * BN;
  const int tid = threadIdx.x;
  const int lane = tid & 63, wid = tid >> 6;
  const int wr = wid >> 2, wc = wid & 3;
  const int lr = lane & 15, hi = lane >> 4;
  const int wrow = wr * (MF * 16), wcol = wc * (NF * 16);

  const half_t* Ab = A + (size_t)brow * K;

  // per-thread B source pointers (row + swizzle constant across K-tiles)
  const float* bp[LB];
#pragma unroll
  for (int l = 0; l < LB; ++l) {
    int c = l * 512 + tid, r = c >> 3, s = c & 7;
    int row = bcol + r;
    const float* src = (row < 4096) ? (Bq + (size_t)row * K)
                     : (row < 5120) ? (Bk + (size_t)(row - 4096) * K)
                                    : (Bv + (size_t)(row - 5120) * K);
    bp[l] = src + ((s ^ (r & 7)) * 8);
  }

  f32x4 acc[MF][NF] = {};
  half8 afr[MH], bfr[NF];
  f32x4 breg[LB][2];

#define STAGE_A(l, k0, buf) { \
    int c_ = (l) * 512 + tid; int r_ = c_ >> 3, s_ = c_ & 7; \
    __builtin_amdgcn_global_load_lds( \
      (cg_void*)(Ab + (size_t)r_ * K + (k0) + ((s_ ^ (r_ & 7)) * 8)), \
      (lds_void*)(&Al[buf][((l) * 512 + wid * 64) * 8]), 16, 0, 0); }
#define LOAD_B_ALL(k0) { \
    _Pragma("unroll") for (int l_ = 0; l_ < LB; ++l_) { \
      breg[l_][0] = *(const f32x4*)(bp[l_] + (k0)); \
      breg[l_][1] = *(const f32x4*)(bp[l_] + (k0) + 4); } }
#define WRITE_B_ALL(buf) { \
    _Pragma("unroll") for (int l_ = 0; l_ < LB; ++l_) { \
      half8 h_; \
      _Pragma("unroll") for (int e_ = 0; e_ < 4; ++e_) { \
        h_[e_] = (half_t)breg[l_][0][e_]; h_[4 + e_] = (half_t)breg[l_][1][e_]; } \
      *(half8*)&Bl[buf][((l_) * 512 + tid) * 8] = h_; } }
#define RD_A(i, mh, kk, buf) { \
    int row_ = wrow + ((mh) * MH + (i)) * 16 + lr; int ks_ = (kk) * 4 + hi; \
    afr[i] = *(const half8*)&Al[buf][row_ * 64 + ((ks_ ^ (row_ & 7)) * 8)]; }
#define RD_B(n, kk, buf) { \
    int row_ = wcol + (n) * 16 + lr; int ks_ = (kk) * 4 + hi; \
    bfr[n] = *(const half8*)&Bl[buf][row_ * 64 + ((ks_ ^ (row_ & 7)) * 8)]; }
#define MFMA_PH(mh) { \
    __builtin_amdgcn_s_setprio(1); \
    _Pragma("unroll") for (int i_ = 0; i_ < MH; ++i_) \
      _Pragma("unroll") for (int n_ = 0; n_ < NF; ++n_) \
        acc[(mh) * MH + i_][n_] = __builtin_amdgcn_mfma_f32_16x16x32_f16( \
            afr[i_], bfr[n_], acc[(mh) * MH + i_][n_], 0, 0, 0); \
    __builtin_amdgcn_s_setprio(0); }

#define DO_TILE(T, BUF) { \
    const int kn_ = ((T) + 1) * 64; const bool pf_ = ((T) + 1) < NT; \
    if (pf_) { _Pragma("unroll") for (int l_ = 0; l_ < LA; ++l_) STAGE_A(l_, kn_, (BUF) ^ 1); } \
    _Pragma("unroll") for (int n_ = 0; n_ < NF; ++n_) RD_B(n_, 0, BUF); \
    _Pragma("unroll") for (int i_ = 0; i_ < MH; ++i_) RD_A(i_, 0, 0, BUF); \
    MFMA_PH(0); \
    __builtin_amdgcn_s_barrier(); __builtin_amdgcn_sched_barrier(0); \
    if (pf_) { LOAD_B_ALL(kn_); } \
    _Pragma("unroll") for (int i_ = 0; i_ < MH; ++i_) RD_A(i_, 1, 0, BUF); \
    MFMA_PH(1); \
    __builtin_amdgcn_s_barrier(); __builtin_amdgcn_sched_barrier(0); \
    _Pragma("unroll") for (int n_ = 0; n_ < NF; ++n_) RD_B(n_, 1, BUF); \
    _Pragma("unroll") for (int i_ = 0; i_ < MH; ++i_) RD_A(i_, 1, 1, BUF); \
    MFMA_PH(1); \
    __builtin_amdgcn_s_barrier(); __builtin_amdgcn_sched_barrier(0); \
    _Pragma("unroll") for (int i_ = 0; i_ < MH; ++i_) RD_A(i_, 0, 1, BUF); \
    MFMA_PH(0); \
    if (pf_) { WRITE_B_ALL((BUF) ^ 1); } \
    asm volatile("s_waitcnt vmcnt(0)" ::: "memory"); \
    __syncthreads(); }

  const int NT = K / 64;
  // prologue: stage tile 0 (A via gload_lds, B via reg+cvt), drain, sync
#pragma unroll
  for (int l_ = 0; l_ < LA; ++l_) STAGE_A(l_, 0, 0);
  LOAD_B_ALL(0);
  WRITE_B_ALL(0);
  asm volatile("s_waitcnt vmcnt(0)" ::: "memory");
  __syncthreads();

  for (int t = 0; t < NT; t += 2) {
    DO_TILE(t, 0);
    DO_TILE(t + 1, 1);
  }

#undef STAGE_A
#undef LOAD_B_ALL
#undef WRITE_B_ALL
#undef RD_A
#undef RD_B
#undef MFMA_PH
#undef DO_TILE

#pragma unroll
  for (int m = 0; m < MF; ++m)
#pragma unroll
    for (int n = 0; n < NF; ++n)
#pragma unroll
      for (int r = 0; r < 4; ++r) {
        int row = brow + wrow + m * 16 + hi * 4 + r;
        int col = bcol + wcol + n * 16 + lr;
        float v = acc[m][n][r];
        if (OUT_HALF) ((half_t*)Cout)[(size_t)row * N + col] = (half_t)v;
        else          ((float*)Cout)[(size_t)row * N + col] = v;
      }
}

// ------- fused causal GQA flash attention: swapped-QK in-register softmax ----
// R10 skeleton (4 waves, QBLK=64, 2-phase prefetch, setprio) with T12:
// sc = mfma(kf, qf) -> lane owns row q=lr: S[q=lr][kv=jt*16+hi*4+r].
// Row max = 15 local fmax + 2 shfl_xor(16,32). P packed via cvt_pkrtz and
// redistributed in-register (16 shfl + 8 sel) into the PV A-operand layout
// P[q=lr][kv=hi*8+e] -- the 16-store/2-read P LDS round-trip is deleted.
// Rescale factors moved to acc rows via 4 width-16 shuffles (rescale tiles
// only, defer-max THR=8). l kept lane-partial; epilogue reduce + remap.
__global__ __launch_bounds__(256, 2) void attn_k(const half_t* __restrict__ QKV,
                                                 const half_t* __restrict__ Vt,
                                                 half_t* __restrict__ Ob) {
  const int bid = blockIdx.x;
  const int qb = 31 - (bid >> 5);   // longest blocks dispatch first
  const int h  = bid & 31;
  const int kh = h >> 2;
  const int tid = threadIdx.x;
  const int lane = tid & 63;
  const int w = tid >> 6;
  const int lr = lane & 15, hi = lane >> 4;
  const int qrow = qb * 64 + w * 16;

  __shared__ half_t Klds[2][64 * 128];   // [kv][128] swizzled-linear
  __shared__ half_t Vlds[2][128 * 64];   // [d][kv]   swizzled-linear

  const half_t* Qp  = QKV + h * HD;
  const half_t* Kp  = QKV + HID + kh * HD;
  const half_t* Vtp = Vt + (size_t)kh * (HD * T_SEQ);

  half8 qf[4];
#pragma unroll
  for (int kk = 0; kk < 4; ++kk)
    qf[kk] = *(const half8*)&Qp[(size_t)(qrow + lr) * QCOLS + kk * 32 + hi * 8];

  f32x4 acc[8] = {};
  float mrow = -1e30f, lrow = 0.0f;   // per-lane row q = qrow + lr

#define STAGE_KV(kv0, buf) { \
    _Pragma("unroll") for (int c_ = 0; c_ < 4; ++c_) { \
      int chunk_ = c_ * 256 + tid; \
      int r_ = chunk_ >> 4, s_ = chunk_ & 15; \
      int cc_ = (s_ & 8) | ((s_ ^ r_) & 7); \
      __builtin_amdgcn_global_load_lds( \
          (cg_void*)(Kp + (size_t)((kv0) + r_) * QCOLS + cc_ * 8), \
          (lds_void*)(&Klds[buf][(c_ * 256 + w * 64) * 8]), 16, 0, 0); } \
    _Pragma("unroll") for (int c_ = 0; c_ < 4; ++c_) { \
      int chunk_ = c_ * 256 + tid; \
      int r_ = chunk_ >> 3, s_ = chunk_ & 7; \
      int cc_ = (s_ ^ r_) & 7; \
      __builtin_amdgcn_global_load_lds( \
          (cg_void*)(Vtp + (size_t)r_ * T_SEQ + (kv0) + cc_ * 8), \
          (lds_void*)(&Vlds[buf][(c_ * 256 + w * 64) * 8]), 16, 0, 0); } }

#define COMPUTE(T, BUF) { \
    const int kv0_ = (T) * 64; \
    f32x4 sc[4] = {}; \
    __builtin_amdgcn_s_setprio(1); \
    _Pragma("unroll") for (int jt_ = 0; jt_ < 4; ++jt_) \
      _Pragma("unroll") for (int kk_ = 0; kk_ < 4; ++kk_) { \
        int srow_ = jt_ * 16 + lr; \
        int sl_ = kk_ * 4 + hi; \
        int c_ = (sl_ & 8) | ((sl_ ^ srow_) & 7); \
        half8 kf_ = *(const half8*)&Klds[BUF][srow_ * 128 + c_ * 8]; \
        sc[jt_] = __builtin_amdgcn_mfma_f32_16x16x32_f16(kf_, qf[kk_], sc[jt_], 0, 0, 0); \
      } \
    __builtin_amdgcn_s_setprio(0); \
    if ((T) == qb) { \
      int ig_ = qrow + lr; \
      _Pragma("unroll") for (int jt_ = 0; jt_ < 4; ++jt_) \
        _Pragma("unroll") for (int r_ = 0; r_ < 4; ++r_) { \
          int jg_ = kv0_ + jt_ * 16 + hi * 4 + r_; \
          if (jg_ > ig_) sc[jt_][r_] = -1e30f; \
        } \
    } \
    float pmax_ = sc[0][0]; \
    _Pragma("unroll") for (int jt_ = 0; jt_ < 4; ++jt_) \
      _Pragma("unroll") for (int r_ = 0; r_ < 4; ++r_) \
        pmax_ = fmaxf(pmax_, sc[jt_][r_]); \
    pmax_ = fmaxf(pmax_, __shfl_xor(pmax_, 16, 64)); \
    pmax_ = fmaxf(pmax_, __shfl_xor(pmax_, 32, 64)); \
    if (__any(pmax_ > mrow + 8.0f)) { \
      float mn_ = fmaxf(mrow, pmax_); \
      float scl_ = __expf(mrow - mn_); \
      mrow = mn_; \
      float ls_ = 0.0f; \
      _Pragma("unroll") for (int jt_ = 0; jt_ < 4; ++jt_) \
        _Pragma("unroll") for (int r_ = 0; r_ < 4; ++r_) { \
          sc[jt_][r_] = __expf(sc[jt_][r_] - mn_); ls_ += sc[jt_][r_]; } \
      lrow = lrow * scl_ + ls_; \
      float sclr_[4]; \
      _Pragma("unroll") for (int r_ = 0; r_ < 4; ++r_) \
        sclr_[r_] = __shfl(scl_, hi * 4 + r_, 16); \
      _Pragma("unroll") for (int g_ = 0; g_ < 8; ++g_) \
        _Pragma("unroll") for (int r_ = 0; r_ < 4; ++r_) acc[g_][r_] *= sclr_[r_]; \
    } else { \
      float ls_ = 0.0f; \
      _Pragma("unroll") for (int jt_ = 0; jt_ < 4; ++jt_) \
        _Pragma("unroll") for (int r_ = 0; r_ < 4; ++r_) { \
          sc[jt_][r_] = __expf(sc[jt_][r_] - mrow); ls_ += sc[jt_][r_]; } \
      lrow += ls_; \
    } \
    /* pack P to fp16 pairs: pk[jt] covers kv = jt*16 + hi*4 + {0..3} */ \
    uint32_t pk_[4][2]; \
    _Pragma("unroll") for (int jt_ = 0; jt_ < 4; ++jt_) { \
      pk_[jt_][0] = pkrtz(sc[jt_][0], sc[jt_][1]); \
      pk_[jt_][1] = pkrtz(sc[jt_][2], sc[jt_][3]); } \
    /* in-register exchange -> PV A-operand: P[q=lr][kv = hi*8+e (+32)] */ \
    const int s0_ = lr + ((hi & 1) << 5); \
    const int s1_ = s0_ + 16; \
    const bool hs_ = ((hi >> 1) & 1) != 0; \
    pfu P0_, P1_; \
    { uint32_t a_ = (uint32_t)__shfl((int)pk_[0][0], s0_, 64); \
      uint32_t b_ = (uint32_t)__shfl((int)pk_[1][0], s0_, 64); P0_.u[0] = hs_ ? b_ : a_; } \
    { uint32_t a_ = (uint32_t)__shfl((int)pk_[0][1], s0_, 64); \
      uint32_t b_ = (uint32_t)__shfl((int)pk_[1][1], s0_, 64); P0_.u[1] = hs_ ? b_ : a_; } \
    { uint32_t a_ = (uint32_t)__shfl((int)pk_[0][0], s1_, 64); \
      uint32_t b_ = (uint32_t)__shfl((int)pk_[1][0], s1_, 64); P0_.u[2] = hs_ ? b_ : a_; } \
    { uint32_t a_ = (uint32_t)__shfl((int)pk_[0][1], s1_, 64); \
      uint32_t b_ = (uint32_t)__shfl((int)pk_[1][1], s1_, 64); P0_.u[3] = hs_ ? b_ : a_; } \
    { uint32_t a_ = (uint32_t)__shfl((int)pk_[2][0], s0_, 64); \
      uint32_t b_ = (uint32_t)__shfl((int)pk_[3][0], s0_, 64); P1_.u[0] = hs_ ? b_ : a_; } \
    { uint32_t a_ = (uint32_t)__shfl((int)pk_[2][1], s0_, 64); \
      uint32_t b_ = (uint32_t)__shfl((int)pk_[3][1], s0_, 64); P1_.u[1] = hs_ ? b_ : a_; } \
    { uint32_t a_ = (uint32_t)__shfl((int)pk_[2][0], s1_, 64); \
      uint32_t b_ = (uint32_t)__shfl((int)pk_[3][0], s1_, 64); P1_.u[2] = hs_ ? b_ : a_; } \
    { uint32_t a_ = (uint32_t)__shfl((int)pk_[2][1], s1_, 64); \
      uint32_t b_ = (uint32_t)__shfl((int)pk_[3][1], s1_, 64); P1_.u[3] = hs_ ? b_ : a_; } \
    __builtin_amdgcn_s_setprio(1); \
    _Pragma("unroll") for (int g_ = 0; g_ < 8; ++g_) { \
      int vrow_ = g_ * 16 + lr; \
      { int c0_ = (hi ^ vrow_) & 7; \
        half8 vf_ = *(const half8*)&Vlds[BUF][vrow_ * 64 + c0_ * 8]; \
        acc[g_] = __builtin_amdgcn_mfma_f32_16x16x32_f16(P0_.h, vf_, acc[g_], 0, 0, 0); } \
      { int c1_ = ((4 + hi) ^ vrow_) & 7; \
        half8 vf_ = *(const half8*)&Vlds[BUF][vrow_ * 64 + c1_ * 8]; \
        acc[g_] = __builtin_amdgcn_mfma_f32_16x16x32_f16(P1_.h, vf_, acc[g_], 0, 0, 0); } \
    } \
    __builtin_amdgcn_s_setprio(0); }

#define TILE_SYNC() { asm volatile("s_waitcnt vmcnt(0)" ::: "memory"); \
                      __builtin_amdgcn_s_barrier(); __builtin_amdgcn_sched_barrier(0); }

  const int nt = qb + 1;
  STAGE_KV(0, 0);
  TILE_SYNC();

  int t = 0;
  for (; t + 2 <= nt; t += 2) {
    STAGE_KV((t + 1) * 64, 1);
    COMPUTE(t, 0);
    TILE_SYNC();
    if (t + 2 < nt) { STAGE_KV((t + 2) * 64, 0); }
    COMPUTE(t + 1, 1);
    TILE_SYNC();
  }
  if (t < nt) { COMPUTE(t, 0); }

#undef STAGE_KV
#undef COMPUTE
#undef TILE_SYNC

  // epilogue: reduce lane-partial l across the row's 4 lanes, remap to acc rows
  float l = lrow;
  l += __shfl_xor(l, 16, 64);
  l += __shfl_xor(l, 32, 64);
  float linv = 1.0f / l;             // per-lane, row q = qrow + lr
  float linvr[4];
#pragma unroll
  for (int r = 0; r < 4; ++r) linvr[r] = __shfl(linv, hi * 4 + r, 16);
#pragma unroll
  for (int g = 0; g < 8; ++g)
#pragma unroll
    for (int r = 0; r < 4; ++r) {
      int row = qrow + hi * 4 + r;
      int col = h * HD + g * 16 + lr;
      Ob[(size_t)row * HID + col] = (half_t)(acc[g][r] * linvr[r]);
    }
}

// ---------------- launch ----------------
extern "C" void kernel_launch(void* const* d_in, const int* in_sizes, int n_in,
                              void* d_out, int out_size, void* d_ws, size_t ws_size,
                              hipStream_t stream) {
  const float* hs = (const float*)d_in[0];
  const float* Wq = (const float*)d_in[1];
  const float* Wk = (const float*)d_in[2];
  const float* Wv = (const float*)d_in[3];
  const float* Wo = (const float*)d_in[4];
  float* out = (float*)d_out;

  char* ws = (char*)d_ws;
  half_t* Xh    = (half_t*)(ws + 0);           // 16 MB (dead after gemm1)
  half_t* Vt    = (half_t*)(ws + 0);           // 4 MB, reuses Xh region
  half_t* QKV   = (half_t*)(ws + 100663296);   // 24 MB [2048][6144]
  half_t* attnh = (half_t*)(ws + 125829120);   // 16 MB [2048][4096]
  float*  cs    = (float*)(ws + 142606336);    // 1 MB cos|sin tables
  if (ws_size < 143654912ull) return;

  cast_x_k<<<8192, 256, 0, stream>>>(hs, Xh);
  rope_tables_k<<<512, 256, 0, stream>>>(cs);

  gemm8p_k<256, 192, 1><<<256, 512, 0, stream>>>(Xh, Wq, Wk, Wv, (void*)QKV, 2048, 6144, 4096);
  rope_vt_k<<<21504, 256, 0, stream>>>(QKV, cs, Vt);
  attn_k<<<1024, 256, 0, stream>>>(QKV, Vt, attnh);
  gemm8p_k<256, 128, 0><<<256, 512, 0, stream>>>(attnh, Wo, Wo, Wo, (void*)out, 2048, 4096, 4096);
}